// Round 8
// baseline (22.004 us; speedup 1.0000x reference)
//
#include <hip/hip_runtime.h>

// TreeLoss: 2-level hierarchical softmax loss.
// z(b)    = 1 + sum_p e^{x_p} * (1 + sum_{c in p} e^{x_c})   (parents p=56..63)
// loss(b) = log(z / (e^{x_g} * e^{x_parent(g)})),  parent(g) = 56 + g/7.
//
// R8 = R7 (barrier-free wave-private staging) + fully vectorized LDS.
// R3/R5/R7 all sat at ~21-23us with ~66 scalar LDS wave-instrs per wave
// (stride 65 broke 16B alignment -> 4x ds_write_b32 per float4; 32x
// ds_read_b32 per half-row). Stride 68 floats (272B, 16B-aligned rows):
//   stage  = 8x ds_write_b128 / lane
//   reduce = 7x ds_read_b128 (children, 112B-aligned) + 1x (parents) / lane
// 66 -> 18 LDS wave-instrs. Banks: 68%32=4, each b128 instr spreads
// 64 lanes x 4 words uniformly = 8/bank = structural minimum.

#define THREADS 256               // 4 waves
#define WROWS   32                // rows per wave
#define RPB     (4 * WROWS)       // 128 rows per block
#define STRIDE  68                // floats; 272B, 16B-aligned

__device__ __forceinline__ float elem(const float4& v, int j) {
    return j == 0 ? v.x : j == 1 ? v.y : j == 2 ? v.z : v.w;
}

__global__ void __launch_bounds__(THREADS) tree_loss_partial(
    const float* __restrict__ pred,   // [rows, 64]
    const int*   __restrict__ gt,     // [rows] 0..55
    float*       __restrict__ partial,// [gridDim.x]
    int rows)
{
    __shared__ float lds[4 * WROWS * STRIDE];   // 34816 B -> 4 blocks/CU
    __shared__ float wsum[4];

    const int t = threadIdx.x;
    const int w = t >> 6;
    const int l = t & 63;
    const int waveRowBase = blockIdx.x * RPB + w * WROWS;
    float* e_base = &lds[w * WROWS * STRIDE];

    // ---- Stage (wave-private): 32 rows = 512 float4 / 64 lanes = 8 each.
    const float4* p4 = (const float4*)pred + (size_t)waveRowBase * 16;
    const bool full = (waveRowBase + WROWS <= rows);
    float4 v[8];
    #pragma unroll
    for (int i = 0; i < 8; ++i) {
        const int f = i * 64 + l;
        v[i] = (full || waveRowBase + (f >> 4) < rows)
                 ? p4[f] : make_float4(0.f, 0.f, 0.f, 0.f);
    }
    #pragma unroll
    for (int i = 0; i < 8; ++i) {
        const int f   = i * 64 + l;
        const int row = f >> 4;
        const int c4  = (f & 15) << 2;
        float4 ef;
        ef.x = __expf(v[i].x); ef.y = __expf(v[i].y);
        ef.z = __expf(v[i].z); ef.w = __expf(v[i].w);
        *(float4*)(e_base + row * STRIDE + c4) = ef;   // ds_write_b128
    }
    // No __syncthreads: same wave wrote, same wave reads (lgkmcnt).

    // ---- Compute: 2 lanes per row; hi=0 -> parents 0-3, hi=1 -> 4-7.
    const int r  = l & 31;
    const int hi = l >> 5;
    const float* e = e_base + r * STRIDE;

    float4 ch[7];
    #pragma unroll
    for (int k = 0; k < 7; ++k)
        ch[k] = *(const float4*)(e + hi * 28 + 4 * k);  // ds_read_b128
    const float4 pv = *(const float4*)(e + 56 + 4 * hi);

    float zh = 0.f;
    #pragma unroll
    for (int p = 0; p < 4; ++p) {
        float s = 1.f;
        #pragma unroll
        for (int c = 0; c < 7; ++c) {
            const int idx = p * 7 + c;          // compile-time after unroll
            s += elem(ch[idx >> 2], idx & 3);
        }
        zh += elem(pv, p) * s;
    }
    const float zo = __shfl_xor(zh, 32);        // other half's partial z

    const int  rowg  = waveRowBase + r;
    const bool valid = (rowg < rows);
    float loss = 0.f;
    if (hi == 0 && valid) {
        const int g = gt[rowg];                 // lanes 0..31: coalesced 128B
        const float z = 1.f + zh + zo;
        const float m = e[g] * e[56 + g / 7];   // 2x ds_read_b32 gather
        loss = __logf(z / m);
    }

    // ---- Wave + block reduction.
    #pragma unroll
    for (int off = 32; off; off >>= 1) loss += __shfl_xor(loss, off);
    if (l == 0) wsum[w] = loss;
    __syncthreads();                             // once per block
    if (t == 0) partial[blockIdx.x] = wsum[0] + wsum[1] + wsum[2] + wsum[3];
}

__global__ void __launch_bounds__(256) tree_loss_final(
    const float* __restrict__ partial, int n,
    float* __restrict__ out, float inv)
{
    float s = 0.0f;
    for (int i = threadIdx.x; i < n; i += 256) s += partial[i];
    #pragma unroll
    for (int off = 32; off; off >>= 1) s += __shfl_xor(s, off);
    __shared__ float w[4];
    const int lane = threadIdx.x & 63;
    const int wv   = threadIdx.x >> 6;
    if (lane == 0) w[wv] = s;
    __syncthreads();
    if (threadIdx.x == 0) out[0] = (w[0] + w[1] + w[2] + w[3]) * inv;
}

extern "C" void kernel_launch(void* const* d_in, const int* in_sizes, int n_in,
                              void* d_out, int out_size, void* d_ws, size_t ws_size,
                              hipStream_t stream) {
    const float* pred = (const float*)d_in[0];   // [B,64] fp32
    const int*   gt   = (const int*)d_in[1];     // [B] int32
    float* out     = (float*)d_out;
    float* partial = (float*)d_ws;
    const int rows = in_sizes[1];                // BATCH = 262144

    const int blocks = (rows + RPB - 1) / RPB;   // 2048
    tree_loss_partial<<<blocks, THREADS, 0, stream>>>(pred, gt, partial, rows);
    tree_loss_final<<<1, 256, 0, stream>>>(partial, blocks, out, 1.0f / (float)rows);
}